// Round 11
// baseline (55.428 us; speedup 1.0000x reference)
//
#include <hip/hip_runtime.h>

// K-manifold AE cluster objective — ROUND 11: 4-way pipeline split (ablation).
// out = mean_b min_k [ ||x_b||^2 - 2 w.z + z^T G z + lamb*reg_k ]
// setup_k: pack W frags + G/lreg + zero cnt
// pack_a : x (fp32) -> bf16 A fragments in ws + exact rowsq
// gemm_k : Y = A @ W, pure MFMA, A+B staged via global_load_lds DMA
// epi_k  : per-(row,k) objective, min_k, mean reduce (last-block finalize)

#define KCLUST   16
#define DAMB     512
#define DLAT     10
#define BATCH    16384
#define LAMBDA   0.01f
#define NKS      16            // 512/32 k-steps
#define NNT      20            // 320/16 n-tiles
#define CHB      40960         // bytes per B chunk (2 ks x 20 nt x 64 x 16B)
#define NBLK_E   256           // epi blocks

typedef __attribute__((ext_vector_type(8))) short short8;
typedef __attribute__((ext_vector_type(4))) float f32x4;

__device__ inline short f2bf(float f) {
    unsigned u = __builtin_bit_cast(unsigned, f);
    unsigned r = (u + 0x7FFFu + ((u >> 16) & 1u)) >> 16;
    return (short)r;
}

// ---------------- setup: blocks 0..79 pack W frags; 80..95 G/lreg; zero cnt
__global__ __launch_bounds__(256) void setup_k(const float* __restrict__ Us,
                                               const float* __restrict__ Vs,
                                               short* __restrict__ wpack,
                                               float* __restrict__ G,
                                               float* __restrict__ lreg,
                                               unsigned* __restrict__ cnt) {
    __shared__ float Ul[DAMB * DLAT];    // 20 KB (G branch only)
    __shared__ float red[256];
    int b = blockIdx.x;
    int tid = threadIdx.x;
    if (b == 0 && tid == 0)
        __hip_atomic_store(cnt, 0u, __ATOMIC_RELEASE, __HIP_MEMORY_SCOPE_AGENT);
    if (b < 80) {
        int idx  = b * 256 + tid;                  // [0, 16*20*64)
        int ks   = idx / (NNT * 64);
        int rem  = idx % (NNT * 64);
        int nt   = rem / 64;
        int lane = rem % 64;
        int col  = nt * 16 + (lane & 15);
        int cl   = col / 20;
        int c    = col % 20;
        short8 sv;
#pragma unroll
        for (int j = 0; j < 8; ++j) {
            int k = ks * 32 + (lane >> 4) * 8 + j;
            float v;
            if (c < DLAT) v = Vs[(size_t)cl * DLAT * DAMB + c * DAMB + k];
            else          v = Us[(size_t)cl * DAMB * DLAT + k * DLAT + (c - DLAT)];
            sv[j] = f2bf(v);
        }
        *(short8*)&wpack[(size_t)idx * 8] = sv;
    } else {
        int k = b - 80;
        const float* Uk = Us + (size_t)k * DAMB * DLAT;
        const float* Vk = Vs + (size_t)k * DLAT * DAMB;
        float s = 0.f;
        for (int i = tid; i < DAMB * DLAT; i += 256) {
            float a = Uk[i], bb = Vk[i];
            Ul[i] = a;
            s += a * a + bb * bb;
        }
        red[tid] = s;
        __syncthreads();
        for (int st = 128; st > 0; st >>= 1) {
            if (tid < st) red[tid] += red[tid + st];
            __syncthreads();
        }
        if (tid == 0) lreg[k] = LAMBDA * 0.5f * red[0];
        if (tid < DLAT * DLAT) {
            int i = tid / DLAT, j = tid % DLAT;
            float g = 0.f;
#pragma unroll 8
            for (int d = 0; d < DAMB; ++d)
                g = fmaf(Ul[d * DLAT + i], Ul[d * DLAT + j], g);
            G[k * 100 + tid] = g;
        }
    }
}

// ---------------- pack_a: 1024 blocks x 256 thr; block = one 16-row m-tile
// apack[mt][ks][ln][8]: ln=(lh<<4)|row, element e -> A[mt*16+row][ks*32+lh*8+e]
__global__ __launch_bounds__(256) void pack_a(const float* __restrict__ x,
                                              short* __restrict__ apack,
                                              float* __restrict__ rowsq) {
    __shared__ float rsq[16][16];
    const int mt   = blockIdx.x;
    const int srow = threadIdx.x >> 4;     // 0..15
    const int sc   = threadIdx.x & 15;     // 0..15
    const float* xr = x + ((size_t)mt * 16 + srow) * DAMB;
    float rs = 0.f;
#pragma unroll
    for (int i = 0; i < 4; ++i) {
        int k8 = sc + 16 * i;               // 8-float group, 0..63
        float4 v0 = *(const float4*)(xr + k8 * 8);
        float4 v1 = *(const float4*)(xr + k8 * 8 + 4);
        rs += v0.x * v0.x + v0.y * v0.y + v0.z * v0.z + v0.w * v0.w
            + v1.x * v1.x + v1.y * v1.y + v1.z * v1.z + v1.w * v1.w;
        short8 sv;
        sv[0] = f2bf(v0.x); sv[1] = f2bf(v0.y); sv[2] = f2bf(v0.z); sv[3] = f2bf(v0.w);
        sv[4] = f2bf(v1.x); sv[5] = f2bf(v1.y); sv[6] = f2bf(v1.z); sv[7] = f2bf(v1.w);
        int ks = k8 >> 2, lh = k8 & 3;
        int ln = (lh << 4) | srow;
        *(short8*)&apack[(size_t)(((mt * NKS + ks) * 64 + ln)) * 8] = sv;
    }
    rsq[srow][sc] = rs;
    __syncthreads();
    if (threadIdx.x < 16) {
        float s = 0.f;
#pragma unroll
        for (int j = 0; j < 16; ++j) s += rsq[threadIdx.x][j];
        rowsq[mt * 16 + threadIdx.x] = s;
    }
}

__device__ __forceinline__ void gload_lds16(const void* g, void* l) {
    __builtin_amdgcn_global_load_lds(
        (const __attribute__((address_space(1))) unsigned int*)g,
        (__attribute__((address_space(3))) unsigned int*)l, 16, 0, 0);
}

template <int N> __device__ __forceinline__ void waitv() {
    if constexpr (N == 0)      asm volatile("s_waitcnt vmcnt(0)" ::: "memory");
    else if constexpr (N == 5) asm volatile("s_waitcnt vmcnt(5)" ::: "memory");
    __builtin_amdgcn_sched_barrier(0);   // rule #18
}

// ---------------- gemm_k: 256 blocks x 512 thr (8 waves: 2M x 4N), BM=64
// All operand traffic via global_load_lds DMA; zero VGPR-return global loads.
__global__ __launch_bounds__(512) void gemm_k(const short* __restrict__ apack,
                                              const short* __restrict__ wpack,
                                              float* __restrict__ Y) {
    __shared__ __align__(16) char a_lds[65536];       // 4 m-tiles x 16 ks x 1KB
    __shared__ __align__(16) char b_lds[2 * CHB];     // B double buffer

    const int tid  = threadIdx.x;
    const int lane = tid & 63;
    const int wv   = tid >> 6;                  // 0..7
    const int mw   = wv >> 2;                   // 0..1
    const int nw   = wv & 3;                    // 0..3
    const int row0 = blockIdx.x * 64;

    // stage A (64 KB, linear copy; dest = uniform-base + lane*16)
    const char* asrc = (const char*)apack + (size_t)blockIdx.x * 65536;
#pragma unroll
    for (int r = 0; r < 8; ++r)
        gload_lds16(asrc + r * 8192 + tid * 16, a_lds + r * 8192 + tid * 16);
    __builtin_amdgcn_sched_barrier(0);

    const char* wsrc = (const char*)wpack;
    const int soff = (wv * 5) * 1024 + lane * 16;

#define ISSUE(c) do { \
        const char* s_ = wsrc + (size_t)(c) * CHB + soff; \
        char* d_ = b_lds + ((c) & 1) * CHB + soff; \
        gload_lds16(s_ + 0,    d_ + 0); \
        gload_lds16(s_ + 1024, d_ + 1024); \
        gload_lds16(s_ + 2048, d_ + 2048); \
        gload_lds16(s_ + 3072, d_ + 3072); \
        gload_lds16(s_ + 4096, d_ + 4096); \
        __builtin_amdgcn_sched_barrier(0); \
    } while (0)

    f32x4 acc[2][5];
#pragma unroll
    for (int m = 0; m < 2; ++m)
#pragma unroll
        for (int j = 0; j < 5; ++j) acc[m][j] = (f32x4)0.f;

#define KSTEP(c, VM) do { \
        waitv<VM>(); \
        __builtin_amdgcn_s_barrier(); \
        __builtin_amdgcn_sched_barrier(0); \
        const short* B_ = (const short*)(b_lds + ((c) & 1) * CHB); \
        _Pragma("unroll") \
        for (int ksl = 0; ksl < 2; ++ksl) { \
            short8 a0 = *(short8*)&a_lds[((((mw * 2 + 0) * NKS + (c) * 2 + ksl) * 64 + lane)) * 16]; \
            short8 a1 = *(short8*)&a_lds[((((mw * 2 + 1) * NKS + (c) * 2 + ksl) * 64 + lane)) * 16]; \
            _Pragma("unroll") \
            for (int j = 0; j < 5; ++j) { \
                short8 bf = *(short8*)&B_[((ksl * NNT + nw * 5 + j) * 64 + lane) * 8]; \
                acc[0][j] = __builtin_amdgcn_mfma_f32_16x16x32_bf16(a0, bf, acc[0][j], 0, 0, 0); \
                acc[1][j] = __builtin_amdgcn_mfma_f32_16x16x32_bf16(a1, bf, acc[1][j], 0, 0, 0); \
            } \
        } \
        __builtin_amdgcn_sched_barrier(0); \
        __builtin_amdgcn_s_barrier(); \
        __builtin_amdgcn_sched_barrier(0); \
    } while (0)

    ISSUE(0); ISSUE(1);
    KSTEP(0, 5); ISSUE(2);
    KSTEP(1, 5); ISSUE(3);
    KSTEP(2, 5); ISSUE(4);
    KSTEP(3, 5); ISSUE(5);
    KSTEP(4, 5); ISSUE(6);
    KSTEP(5, 5); ISSUE(7);
    KSTEP(6, 5);
    KSTEP(7, 0);

#undef KSTEP
#undef ISSUE

    // Y store. C/D layout: col = lane&15, row = (lane>>4)*4 + r
#pragma unroll
    for (int m = 0; m < 2; ++m) {
        int rowb = row0 + mw * 32 + m * 16 + (lane >> 4) * 4;
        int colb = (nw * 5) * 16 + (lane & 15);
#pragma unroll
        for (int j = 0; j < 5; ++j)
#pragma unroll
            for (int r = 0; r < 4; ++r)
                Y[(size_t)(rowb + r) * 320 + colb + j * 16] = acc[m][j][r];
    }
}

// ---------------- epi_k: 256 blocks x 256 thr; block = 64 rows; thread = (row, 4 clusters)
__global__ __launch_bounds__(256) void epi_k(const float* __restrict__ Y,
                                             const float* __restrict__ G,
                                             const float* __restrict__ lreg,
                                             const float* __restrict__ rowsq,
                                             float* __restrict__ parts,
                                             unsigned* __restrict__ cnt,
                                             float* __restrict__ out) {
    __shared__ float Gs[KCLUST * 100];
    __shared__ float lr[KCLUST];
    __shared__ float rmin[64];
    __shared__ int   isLast;

    const int tid = threadIdx.x;
    for (int i = tid; i < KCLUST * 100; i += 256) Gs[i] = G[i];
    if (tid < KCLUST) lr[tid] = lreg[tid];
    __syncthreads();

    const int row = blockIdx.x * 64 + (tid >> 2);
    const int cg  = tid & 3;                     // clusters cg*4 .. +3
    const float* yb = Y + (size_t)row * 320 + cg * 80;

    float m = 3.4e38f;
#pragma unroll
    for (int q = 0; q < 4; ++q) {
        const float* yy = yb + q * 20;
        float4 v0 = *(const float4*)(yy + 0);
        float4 v1 = *(const float4*)(yy + 4);
        float4 v2 = *(const float4*)(yy + 8);
        float4 v3 = *(const float4*)(yy + 12);
        float4 v4 = *(const float4*)(yy + 16);
        float z[DLAT] = {v0.x, v0.y, v0.z, v0.w, v1.x, v1.y, v1.z, v1.w, v2.x, v2.y};
        float w[DLAT] = {v2.z, v2.w, v3.x, v3.y, v3.z, v3.w, v4.x, v4.y, v4.z, v4.w};
        int kk = cg * 4 + q;
        const float* Gk = Gs + kk * 100;
        float s = 0.f, wz = 0.f;
#pragma unroll
        for (int a = 0; a < DLAT; ++a) {
            float gz = 0.f;
#pragma unroll
            for (int b2 = 0; b2 < DLAT; ++b2) gz = fmaf(Gk[a * DLAT + b2], z[b2], gz);
            s  = fmaf(z[a], gz, s);
            wz = fmaf(w[a], z[a], wz);
        }
        m = fminf(m, s - 2.f * wz + lr[kk]);
    }
    // min across the 4 lanes sharing a row
    m = fminf(m, __shfl_xor(m, 1));
    m = fminf(m, __shfl_xor(m, 2));
    if (cg == 0) rmin[tid >> 2] = m + rowsq[row];
    __syncthreads();

    if (tid < 64) {
        float v = rmin[tid];
#pragma unroll
        for (int off = 32; off > 0; off >>= 1) v += __shfl_down(v, off);
        if (tid == 0) {
            __hip_atomic_store(&parts[blockIdx.x], v, __ATOMIC_RELEASE,
                               __HIP_MEMORY_SCOPE_AGENT);
            unsigned prev = __hip_atomic_fetch_add(cnt, 1u, __ATOMIC_ACQ_REL,
                                                   __HIP_MEMORY_SCOPE_AGENT);
            isLast = (prev == NBLK_E - 1);
        }
    }
    __syncthreads();
    if (isLast && tid < 64) {
        float s = 0.f;
#pragma unroll
        for (int q = 0; q < NBLK_E / 64; ++q)
            s += __hip_atomic_load(&parts[tid + q * 64], __ATOMIC_RELAXED,
                                   __HIP_MEMORY_SCOPE_AGENT);
#pragma unroll
        for (int off = 32; off > 0; off >>= 1) s += __shfl_down(s, off);
        if (tid == 0) out[0] = s * (1.0f / BATCH);
    }
}

extern "C" void kernel_launch(void* const* d_in, const int* in_sizes, int n_in,
                              void* d_out, int out_size, void* d_ws, size_t ws_size,
                              hipStream_t stream) {
    const float* x  = (const float*)d_in[0];   // 16384 x 512
    const float* Us = (const float*)d_in[1];   // 16 x 512 x 10
    const float* Vs = (const float*)d_in[2];   // 16 x 10 x 512
    float* out = (float*)d_out;

    // workspace layout (bytes):
    char* wsb = (char*)d_ws;
    short* wpack = (short*)wsb;                        // 327,680 B
    short* apack = (short*)(wsb + 327680);             // 16 MB
    float* Y     = (float*)(wsb + 17104896);           // 21 MB
    float* G     = (float*)(wsb + 38076416);           // 6.4 KB
    float* lreg  = G + KCLUST * 100;
    float* rowsq = lreg + KCLUST;                      // 64 KB
    float* parts = rowsq + BATCH;
    unsigned* cnt = (unsigned*)(parts + NBLK_E);

    setup_k<<<96, 256, 0, stream>>>(Us, Vs, wpack, G, lreg, cnt);
    pack_a<<<BATCH / 16, 256, 0, stream>>>(x, apack, rowsq);
    gemm_k<<<BATCH / 64, 512, 0, stream>>>(apack, wpack, Y);
    epi_k<<<NBLK_E, 256, 0, stream>>>(Y, G, lreg, rowsq, parts, cnt, out);
}